// Round 4
// baseline (126.243 us; speedup 1.0000x reference)
//
#include <hip/hip_runtime.h>
#include <cstdint>
#include <math.h>

#define KN 128
#define BATCH 16
#define CAND 64

typedef float vfloat4 __attribute__((ext_vector_type(4)));

// Output layout (floats), in reference return order:
// tokens (B,C,4) | rel (B,C,K,K) | acyclic (B,C) | dists (2,B,K,K)
static constexpr size_t TOK_OFF = 0;
static constexpr size_t REL_OFF = (size_t)BATCH * CAND * 4;                     // 4096
static constexpr size_t ACY_OFF = REL_OFF + (size_t)BATCH * CAND * KN * KN;    // 16781312
static constexpr size_t DST_OFF = ACY_OFF + (size_t)BATCH * CAND;              // 16782336

// Diagonal sentinel for dmin: must be large but FINITE after a bf16 round-trip
// (FLT_MAX rounds up to +inf in bf16 -> |inf-inf|=nan in the checker).
#define DIAG_BIG 1.0e30f

// Light barrier: orders LDS producer->consumer across the block WITHOUT
// draining vmcnt. __syncthreads lowers to "s_waitcnt vmcnt(0) lgkmcnt(0);
// s_barrier", which would drain the next matrix's prefetch loads at every
// phase boundary and forbid read/write overlap (T4 counted-wait principle).
// sched_barrier(0) on both sides pins LDS ops to their side of the barrier
// (rule #18: inline-asm waitcnt alone does not fence register-only reorder).
#define LBAR() do {                                         \
    __builtin_amdgcn_sched_barrier(0);                      \
    asm volatile("s_waitcnt lgkmcnt(0)" ::: "memory");      \
    __builtin_amdgcn_s_barrier();                           \
    __builtin_amdgcn_sched_barrier(0);                      \
} while (0)

// ---------------- Kernel A: base bits prepass + dists ----------------
__global__ __launch_bounds__(256) void prep_kernel(const float* __restrict__ A_t,
                                                   const float* __restrict__ feat,
                                                   uint32_t* __restrict__ bits,
                                                   float* __restrict__ out) {
    int t = threadIdx.x;
    // base bits: 4096 half-rows across 1024 blocks
    {
        int tid  = blockIdx.x * 256 + t;
        int wave = tid >> 6;
        int lane = tid & 63;
        int half = wave & 1;
        int row  = wave >> 1;       // b*128 + i
        float v = A_t[(size_t)row * KN + half * 64 + lane];
        unsigned long long m = __ballot(v > 0.5f);
        if (lane == 0) {
            bits[row * 4 + half * 2]     = (uint32_t)m;
            bits[row * 4 + half * 2 + 1] = (uint32_t)(m >> 32);
        }
    }
    // dists: 2 rows per block
    {
        int bi = 2 * blockIdx.x + (t >> 7);    // 0..2047 = b*K + i
        int b2 = bi >> 7, i = bi & 127, j = t & 127;
        const float* fi = feat + (size_t)bi * 6;
        const float* fj = feat + (size_t)(b2 * KN + j) * 6;
        float pix = fi[0], piy = fi[1], vix = fi[3], viy = fi[4];
        float pjx = fj[0], pjy = fj[1], vjx = fj[3], vjy = fj[4];
        float dx = pix - pjx, dy = piy - pjy;
        float d = sqrtf(dx * dx + dy * dy);
        float rx = pjx - pix, ry = pjy - piy;
        float vx = vjx - vix, vy = vjy - viy;
        float vv = vx * vx + vy * vy;
        float rv = rx * vx + ry * vy;
        float ts = fminf(fmaxf(-rv / (vv + 1e-6f), 0.0f), 3.0f);
        float mx = rx + vx * ts, my = ry + vy * ts;
        float dmin = (i == j) ? DIAG_BIG : sqrtf(mx * mx + my * my);
        float* o = out + DST_OFF;
        __builtin_nontemporal_store(d,    o + (size_t)(b2 * KN + i) * KN + j);
        __builtin_nontemporal_store(dmin, o + (size_t)((BATCH + b2) * KN + i) * KN + j);
    }
}

// ---------------- Main kernel: one 256-thread block per PAIR (bc, bc+1) ------
// R3 pipeline: grid 512; each block processes two matrices sharing b.
// After packing m0 into LDS, ALL of m1's loads are issued; light barriers
// (lgkmcnt-only) keep them in flight while m0 is transposed/stored — so m1's
// 67 MB read stream overlaps m0's 67 MB rel write stream. Counters (R3):
// main was 44.4 us at ~3.0 TB/s combined vs a 21 us / 6.3 TB/s floor, with
// reads and writes in disjoint lockstep bursts.
__global__ __launch_bounds__(256, 2) void main_kernel(const float* __restrict__ cand,
                                                      const float* __restrict__ mask,
                                                      const uint32_t* __restrict__ baseBits,
                                                      float* __restrict__ out) {
    __shared__ uint32_t adj[KN][5];     // row bitmask: adj[i][w] bit k = cb[i][32w+k]
    __shared__ uint32_t adjT[KN][6];    // col bitmask: adjT[c][w] bit k = cb[32w+k][c]
    __shared__ uint32_t baseB[KN][4];
    __shared__ uint32_t validW[4];
    __shared__ uint32_t remW[4];
    __shared__ uint32_t removedW2[2][4];
    __shared__ int      minIdx2[2];

    const int t    = threadIdx.x;
    const int lane = t & 63;
    const int wave = t >> 6;
    const int pair = blockIdx.x;        // 0..511
    const int bc0  = pair * 2;          // even; bc0 and bc0+1 share b
    const int b    = bc0 >> 6;

    const float* cptr0 = cand + (size_t)bc0 * (KN * KN);
    const float* cptr1 = cptr0 + (KN * KN);
    float* relp0 = out + REL_OFF + (size_t)bc0 * (KN * KN);
    float* relp1 = relp0 + (KN * KN);

    // ---- small loads FIRST so their vmcnt retire doesn't wait on the burst --
    if (t == 0) { minIdx2[0] = 0x7fffffff; minIdx2[1] = 0x7fffffff; }
    if (t < 8)  ((uint32_t*)removedW2)[t] = 0;
    {
        uint32_t w0 = baseBits[b * 512 + t];
        uint32_t w1 = baseBits[b * 512 + 256 + t];
        ((uint32_t*)baseB)[t]       = w0;     // flat word w <-> baseB[w>>2][w&3]
        ((uint32_t*)baseB)[t + 256] = w1;
    }
    if (wave < 2) {
        float mv = mask[b * KN + wave * 64 + lane];
        unsigned long long m = __ballot(mv > 0.5f);
        if (lane == 0) {
            validW[wave * 2]     = (uint32_t)m;
            validW[wave * 2 + 1] = (uint32_t)(m >> 32);
        }
    }

    const int sub = lane & 31;

    // ---- issue ALL m0 loads (16-deep MLP) ----
    float4 c0[16];
    #pragma unroll
    for (int m = 0; m < 16; ++m) {
        int r = (m * 4 + wave) * 2 + (lane >> 5);
        c0[m] = ((const float4*)(cptr0 + (size_t)r * KN))[sub];
    }

    // ================= phase bodies ==========================================
    auto pack = [&](const float4* cc) {
        #pragma unroll
        for (int m = 0; m < 16; ++m) {
            int r = (m * 4 + wave) * 2 + (lane >> 5);
            const float4 v = cc[m];
            uint32_t nib = (v.x > 0.5f ? 1u : 0u) | (v.y > 0.5f ? 2u : 0u) |
                           (v.z > 0.5f ? 4u : 0u) | (v.w > 0.5f ? 8u : 0u);
            uint32_t word = nib << (4 * (sub & 7));
            word |= __shfl_xor(word, 1);
            word |= __shfl_xor(word, 2);
            word |= __shfl_xor(word, 4);
            if ((lane & 7) == 0) adj[r][sub >> 3] = word;
        }
    };

    auto transpose = [&]() {
        const int h = wave >> 1, q = wave & 1;
        uint32_t rw0 = adj[h * 64 + lane][q * 2];
        uint32_t rw1 = adj[h * 64 + lane][q * 2 + 1];
        uint32_t myLo = 0, myHi = 0;
        #pragma unroll
        for (int cc = 0; cc < 64; ++cc) {
            uint32_t w = (cc < 32) ? rw0 : rw1;
            unsigned long long m = __ballot((w >> (cc & 31)) & 1u);
            if (lane == cc) { myLo = (uint32_t)m; myHi = (uint32_t)(m >> 32); }
        }
        adjT[q * 64 + lane][2 * h]     = myLo;
        adjT[q * 64 + lane][2 * h + 1] = myHi;
    };

    auto rel_expand = [&](float* relp) {
        // Bit->float via multiply-spread into a byte-packed word; clang emits
        // v_cvt_f32_ubyte{0..3} for (float)(uint8_t)(x>>8k).
        #pragma unroll
        for (int m = 0; m < 16; ++m) {
            int q  = t + 256 * m;        // float4 index 0..4095
            int i  = q >> 5;             // row
            int j0 = (q & 31) * 4;       // starting col
            int iw = j0 >> 5, sh = j0 & 31;
            uint32_t wij = adj[i][iw];           // cb[i][j0..]
            uint32_t wti = adjT[i][iw];          // cb[j0..][i]
            uint32_t a4 = (wij >> sh) & 0xFu;
            uint32_t b4 = (wti >> sh) & 0xFu;
            uint32_t packed = ((a4 * 0x00204081u) & 0x01010101u)
                            | (((b4 * 0x00204081u) & 0x01010101u) << 1);
            vfloat4 o;
            o.x = (float)(uint8_t)(packed);
            o.y = (float)(uint8_t)(packed >> 8);
            o.z = (float)(uint8_t)(packed >> 16);
            o.w = (float)(uint8_t)(packed >> 24);
            __builtin_nontemporal_store(o, ((vfloat4*)relp) + q);
        }
    };

    auto logic = [&](int bcX, int km) {
        // Edit-token scan: min linear index of differing upper-triangle pair
        #pragma unroll
        for (int rep = 0; rep < 2; ++rep) {
            int idx = t + rep * 256;
            int i = idx >> 2, k = idx & 3;
            uint32_t diff = adj[i][k] ^ baseB[i][k];
            if (diff) {
                int base = k * 32;
                uint32_t up, low;
                if (i < base)            { up = diff; low = 0u; }
                else if (i >= base + 31) { up = 0u; low = (i > base + 31) ? diff : (diff & 0x7fffffffu); }
                else {
                    int s = i - base;    // 1..30
                    up  = diff & (0xffffffffu << (s + 1));
                    low = diff & ((1u << s) - 1u);
                }
                int c1 = 0x7fffffff, c2 = 0x7fffffff;
                if (up)  c1 = (i << 7) | (base + __builtin_ctz(up));
                if (low) { int cc2 = base + __builtin_ctz(low); c2 = (cc2 << 7) | i; }
                int cm = min(c1, c2);
                if (cm != 0x7fffffff) atomicMin(&minIdx2[km], cm);
            }
        }
        LBAR();   // minIdx final

        // Token write (reads adj/baseB LDS — both stable through this phase)
        if (t == 0) {
            float* tok = out + TOK_OFF + (size_t)bcX * 4;
            int mi = minIdx2[km];
            if (mi != 0x7fffffff) {
                int i = mi >> 7, j = mi & 127;
                uint32_t b_ij = (baseB[i][j >> 5] >> (j & 31)) & 1u;
                uint32_t b_ji = (baseB[j][i >> 5] >> (i & 31)) & 1u;
                uint32_t c_ij = (adj[i][j >> 5] >> (j & 31)) & 1u;
                uint32_t c_ji = (adj[j][i >> 5] >> (i & 31)) & 1u;
                int prev = (b_ij && !b_ji) ? 1 : ((b_ji && !b_ij) ? 2 : 0);
                int nxt  = (c_ij && !c_ji) ? 1 : ((c_ji && !c_ij) ? 2 : 0);
                tok[0] = (float)i; tok[1] = (float)j; tok[2] = (float)prev; tok[3] = (float)nxt;
            } else {
                tok[0] = 0.f; tok[1] = 0.f; tok[2] = 0.f; tok[3] = 0.f;
            }
        }

        // Per-node registers for Kahn (nodes on threads 0..127)
        uint32_t cT0 = 0, cT1 = 0, cT2 = 0, cT3 = 0;
        int  indeg = 0;
        bool validT = false;
        if (t < KN) {
            cT0 = adjT[t][0]; cT1 = adjT[t][1]; cT2 = adjT[t][2]; cT3 = adjT[t][3];
            validT = (validW[t >> 5] >> (t & 31)) & 1u;
            indeg = validT ? (__popc(cT0) + __popc(cT1) + __popc(cT2) + __popc(cT3)) : 0;
        }

        // Kahn peeling: dec via popc of column masks (early-exit = fixed point)
        bool removed = false;
        for (int it = 0; it < KN; ++it) {
            bool rem = (t < KN) && validT && !removed && (indeg == 0);
            unsigned long long m = __ballot(rem);
            if (wave < 2 && lane == 0) {
                remW[wave * 2]     = (uint32_t)m;
                remW[wave * 2 + 1] = (uint32_t)(m >> 32);
            }
            LBAR();
            uint32_t r0 = remW[0], r1 = remW[1], r2 = remW[2], r3 = remW[3];
            if ((r0 | r1 | r2 | r3) == 0u) break;   // block-uniform
            if (t < 4) removedW2[km][t] |= remW[t];
            if (t < KN) {
                indeg -= __popc(r0 & cT0) + __popc(r1 & cT1) +
                         __popc(r2 & cT2) + __popc(r3 & cT3);
                removed = removed || rem;
            }
            LBAR();
        }
        LBAR();   // removedW2 final

        if (t == 0) {
            int rc = __popc(removedW2[km][0]) + __popc(removedW2[km][1]) +
                     __popc(removedW2[km][2]) + __popc(removedW2[km][3]);
            int vc = __popc(validW[0]) + __popc(validW[1]) +
                     __popc(validW[2]) + __popc(validW[3]);
            out[ACY_OFF + bcX] = ((rc == vc) || (vc <= 1)) ? 1.0f : 0.0f;
        }
    };

    // ================= pipeline ==============================================
    pack(c0);

    // Prefetch m1 NOW — stays in flight across all light barriers; the
    // compiler emits the vmcnt wait only at pack(c1)'s first use.
    float4 c1[16];
    #pragma unroll
    for (int m = 0; m < 16; ++m) {
        int r = (m * 4 + wave) * 2 + (lane >> 5);
        c1[m] = ((const float4*)(cptr1 + (size_t)r * KN))[sub];
    }

    LBAR();              // adj, baseB, validW, inits visible
    transpose();
    LBAR();              // adjT visible

    // Parity by bit 8: co-resident pair (i, i+256) gets opposite order.
    const int par = (pair >> 8) & 1;
    if (par == 0) { rel_expand(relp0); logic(bc0, 0); }
    else          { logic(bc0, 0);     rel_expand(relp0); }

    LBAR();              // adj/adjT reads of m0 done — safe to overwrite
    pack(c1);
    LBAR();              // adj(m1) visible
    transpose();
    LBAR();              // adjT(m1) visible

    // Alternate inner order so each block spreads its own store phases too.
    if (par == 0) { logic(bc0 + 1, 1); rel_expand(relp1); }
    else          { rel_expand(relp1); logic(bc0 + 1, 1); }
}

extern "C" void kernel_launch(void* const* d_in, const int* in_sizes, int n_in,
                              void* d_out, int out_size, void* d_ws, size_t ws_size,
                              hipStream_t stream) {
    const float* A_t  = (const float*)d_in[0];
    const float* cand = (const float*)d_in[1];
    const float* feat = (const float*)d_in[2];
    const float* mask = (const float*)d_in[3];
    float* out = (float*)d_out;
    uint32_t* bits = (uint32_t*)d_ws;   // B*K*4 words = 8 KB

    prep_kernel<<<1024, 256, 0, stream>>>(A_t, feat, bits, out);
    main_kernel<<<(BATCH * CAND) / 2, 256, 0, stream>>>(cand, mask, bits, out);
}

// Round 5
// 123.402 us; speedup vs baseline: 1.0230x; 1.0230x over previous
//
#include <hip/hip_runtime.h>
#include <cstdint>
#include <math.h>

#define KN 128
#define BATCH 16
#define CAND 64

typedef float vfloat4 __attribute__((ext_vector_type(4)));

// Output layout (floats), in reference return order:
// tokens (B,C,4) | rel (B,C,K,K) | acyclic (B,C) | dists (2,B,K,K)
static constexpr size_t TOK_OFF = 0;
static constexpr size_t REL_OFF = (size_t)BATCH * CAND * 4;                     // 4096
static constexpr size_t ACY_OFF = REL_OFF + (size_t)BATCH * CAND * KN * KN;    // 16781312
static constexpr size_t DST_OFF = ACY_OFF + (size_t)BATCH * CAND;              // 16782336

// Diagonal sentinel for dmin: must be large but FINITE after a bf16 round-trip
// (FLT_MAX rounds up to +inf in bf16 -> |inf-inf|=nan in the checker).
#define DIAG_BIG 1.0e30f

// ---------------- Kernel A: base bits prepass + dists ----------------
__global__ __launch_bounds__(256) void prep_kernel(const float* __restrict__ A_t,
                                                   const float* __restrict__ feat,
                                                   uint32_t* __restrict__ bits,
                                                   float* __restrict__ out) {
    int t = threadIdx.x;
    // base bits: 4096 half-rows across 1024 blocks
    {
        int tid  = blockIdx.x * 256 + t;
        int wave = tid >> 6;
        int lane = tid & 63;
        int half = wave & 1;
        int row  = wave >> 1;       // b*128 + i
        float v = A_t[(size_t)row * KN + half * 64 + lane];
        unsigned long long m = __ballot(v > 0.5f);
        if (lane == 0) {
            bits[row * 4 + half * 2]     = (uint32_t)m;
            bits[row * 4 + half * 2 + 1] = (uint32_t)(m >> 32);
        }
    }
    // dists: 2 rows per block
    {
        int bi = 2 * blockIdx.x + (t >> 7);    // 0..2047 = b*K + i
        int b2 = bi >> 7, i = bi & 127, j = t & 127;
        const float* fi = feat + (size_t)bi * 6;
        const float* fj = feat + (size_t)(b2 * KN + j) * 6;
        float pix = fi[0], piy = fi[1], vix = fi[3], viy = fi[4];
        float pjx = fj[0], pjy = fj[1], vjx = fj[3], vjy = fj[4];
        float dx = pix - pjx, dy = piy - pjy;
        float d = sqrtf(dx * dx + dy * dy);
        float rx = pjx - pix, ry = pjy - piy;
        float vx = vjx - vix, vy = vjy - viy;
        float vv = vx * vx + vy * vy;
        float rv = rx * vx + ry * vy;
        float ts = fminf(fmaxf(-rv / (vv + 1e-6f), 0.0f), 3.0f);
        float mx = rx + vx * ts, my = ry + vy * ts;
        float dmin = (i == j) ? DIAG_BIG : sqrtf(mx * mx + my * my);
        float* o = out + DST_OFF;
        __builtin_nontemporal_store(d,    o + (size_t)(b2 * KN + i) * KN + j);
        __builtin_nontemporal_store(dmin, o + (size_t)((BATCH + b2) * KN + i) * KN + j);
    }
}

// ---------------- Main kernel: one 256-thread block per (b,c) ----------------
// Parity-staggered phase order. R5 fix: the stagger key is (bc>>8)&1, not
// bc&1. Dispatch is round-robin across 8 XCDs x 32 CUs, so the 4 co-resident
// blocks on one CU are {k, k+256, k+512, k+768} — they all SHARE bc&1, so the
// old key gave zero intra-CU phase interleave (lockstep store bursts). Bit 8
// alternates {0,1,0,1} across the co-resident set: 2 blocks store rel while
// 2 run the barrier-serial logic phase, overlapping write stream with logic.
__global__ __launch_bounds__(256) void main_kernel(const float* __restrict__ cand,
                                                   const float* __restrict__ mask,
                                                   const uint32_t* __restrict__ baseBits,
                                                   float* __restrict__ out) {
    __shared__ uint32_t adj[KN][5];     // row bitmask: adj[i][w] bit k = cb[i][32w+k]
    __shared__ uint32_t adjT[KN][6];    // col bitmask: adjT[c][w] bit k = cb[32w+k][c]
    __shared__ uint32_t baseB[KN][4];
    __shared__ uint32_t validW[4];
    __shared__ uint32_t remW2[2][4];    // double-buffered: 1 barrier per Kahn iter
    __shared__ uint32_t removedW[4];
    __shared__ int      minIdx;

    const int t    = threadIdx.x;
    const int lane = t & 63;
    const int wave = t >> 6;
    const int bc   = blockIdx.x;        // b*64 + c
    const int b    = bc >> 6;

    const float* cptr = cand + (size_t)bc * (KN * KN);
    float* relp = out + REL_OFF + (size_t)bc * (KN * KN);

    // Issue ALL cand loads first (16-deep MLP), retire under independent work
    float4 c[16];
    const int sub = lane & 31;
    #pragma unroll
    for (int m = 0; m < 16; ++m) {
        int r = (m * 4 + wave) * 2 + (lane >> 5);
        c[m] = ((const float4*)(cptr + (size_t)r * KN))[sub];
    }

    if (t == 0) minIdx = 0x7fffffff;
    if (t < 4)  removedW[t] = 0;

    // base bitmask: 512 words (L2-hot, written by prep_kernel)
    for (int w = t; w < 512; w += 256) {
        baseB[w >> 2][w & 3] = baseBits[b * 512 + w];
    }

    // valid mask: wave0 -> nodes 0..63, wave1 -> 64..127
    if (wave < 2) {
        float mv = mask[b * KN + wave * 64 + lane];
        unsigned long long m = __ballot(mv > 0.5f);
        if (lane == 0) {
            validW[wave * 2]     = (uint32_t)m;
            validW[wave * 2 + 1] = (uint32_t)(m >> 32);
        }
    }

    // Pack candidate adjacency rows into LDS
    #pragma unroll
    for (int m = 0; m < 16; ++m) {
        int r = (m * 4 + wave) * 2 + (lane >> 5);
        const float4 v = c[m];
        uint32_t nib = (v.x > 0.5f ? 1u : 0u) | (v.y > 0.5f ? 2u : 0u) |
                       (v.z > 0.5f ? 4u : 0u) | (v.w > 0.5f ? 8u : 0u);
        uint32_t word = nib << (4 * (sub & 7));
        word |= __shfl_xor(word, 1);
        word |= __shfl_xor(word, 2);
        word |= __shfl_xor(word, 4);
        if ((lane & 7) == 0) adj[r][sub >> 3] = word;
    }
    __syncthreads();   // adj, baseB, validW ready

    // 64x64 bit-tile transpose via 6-step shfl_xor butterfly (replaces the
    // 64-ballot loop: ~70 ops/wave vs ~450). Wave w=(h,q): lane l holds
    // X = row (64h+l), cols [64q,64q+64) as a 64-bit value. Level-d swap:
    // exchange (r,c) <-> (r^d, c^d) where (r&d)!=(c&d); levels commute.
    {
        const int h = wave >> 1, q = wave & 1;
        uint32_t lo = adj[h * 64 + lane][q * 2];
        uint32_t hi = adj[h * 64 + lane][q * 2 + 1];
        unsigned long long x = ((unsigned long long)hi << 32) | lo;
        const unsigned long long Lm[6] = {
            0x5555555555555555ull, 0x3333333333333333ull, 0x0F0F0F0F0F0F0F0Full,
            0x00FF00FF00FF00FFull, 0x0000FFFF0000FFFFull, 0x00000000FFFFFFFFull };
        #pragma unroll
        for (int k = 0; k < 6; ++k) {
            const int d = 1 << k;
            const unsigned long long L = Lm[k];
            unsigned long long y = __shfl_xor((unsigned long long)x, d);
            x = (lane & d) ? ((x & ~L) | ((y & ~L) >> d))
                           : ((x & L)  | ((y & L) << d));
        }
        // lane l now holds col (64q+l), rows [64h,64h+64)
        adjT[q * 64 + lane][2 * h]     = (uint32_t)x;
        adjT[q * 64 + lane][2 * h + 1] = (uint32_t)(x >> 32);
    }
    __syncthreads();   // adjT ready

    // Per-node registers for Kahn (nodes on threads 0..127)
    uint32_t cT0 = 0, cT1 = 0, cT2 = 0, cT3 = 0;
    int  indeg = 0;
    bool validT = false;
    if (t < KN) {
        cT0 = adjT[t][0]; cT1 = adjT[t][1]; cT2 = adjT[t][2]; cT3 = adjT[t][3];
        validT = (validW[t >> 5] >> (t & 31)) & 1u;
        indeg = validT ? (__popc(cT0) + __popc(cT1) + __popc(cT2) + __popc(cT3)) : 0;
    }

    // ================= phase bodies (as lambdas; block-uniform call order) ====
    auto rel_expand = [&]() {
        // Bit->float via multiply-spread into a byte-packed word; clang emits
        // v_cvt_f32_ubyte{0..3} for (float)(uint8_t)(x>>8k).
        #pragma unroll
        for (int m = 0; m < 16; ++m) {
            int q  = t + 256 * m;        // float4 index 0..4095
            int i  = q >> 5;             // row
            int j0 = (q & 31) * 4;       // starting col
            int iw = j0 >> 5, sh = j0 & 31;
            uint32_t wij = adj[i][iw];           // cb[i][j0..]
            uint32_t wti = adjT[i][iw];          // cb[j0..][i]
            uint32_t a4 = (wij >> sh) & 0xFu;
            uint32_t b4 = (wti >> sh) & 0xFu;
            uint32_t packed = ((a4 * 0x00204081u) & 0x01010101u)
                            | (((b4 * 0x00204081u) & 0x01010101u) << 1);
            vfloat4 o;
            o.x = (float)(uint8_t)(packed);
            o.y = (float)(uint8_t)(packed >> 8);
            o.z = (float)(uint8_t)(packed >> 16);
            o.w = (float)(uint8_t)(packed >> 24);
            __builtin_nontemporal_store(o, ((vfloat4*)relp) + q);
        }
    };

    auto logic_phase = [&]() {
        // Edit-token scan: min linear index of differing upper-triangle pair
        for (int idx = t; idx < 512; idx += 256) {
            int i = idx >> 2, k = idx & 3;
            uint32_t diff = adj[i][k] ^ baseB[i][k];
            if (diff) {
                int base = k * 32;
                uint32_t up, low;
                if (i < base)            { up = diff; low = 0u; }
                else if (i >= base + 31) { up = 0u; low = (i > base + 31) ? diff : (diff & 0x7fffffffu); }
                else {
                    int s = i - base;    // 1..30
                    up  = diff & (0xffffffffu << (s + 1));
                    low = diff & ((1u << s) - 1u);
                }
                int c1 = 0x7fffffff, c2 = 0x7fffffff;
                if (up)  c1 = (i << 7) | (base + __builtin_ctz(up));
                if (low) { int cc2 = base + __builtin_ctz(low); c2 = (cc2 << 7) | i; }
                int cm = min(c1, c2);
                if (cm != 0x7fffffff) atomicMin(&minIdx, cm);
            }
        }
        __syncthreads();   // minIdx final

        // Token write
        if (t == 0) {
            float* tok = out + TOK_OFF + (size_t)bc * 4;
            int mi = minIdx;
            if (mi != 0x7fffffff) {
                int i = mi >> 7, j = mi & 127;
                uint32_t b_ij = (baseB[i][j >> 5] >> (j & 31)) & 1u;
                uint32_t b_ji = (baseB[j][i >> 5] >> (i & 31)) & 1u;
                uint32_t c_ij = (adj[i][j >> 5] >> (j & 31)) & 1u;
                uint32_t c_ji = (adj[j][i >> 5] >> (i & 31)) & 1u;
                int prev = (b_ij && !b_ji) ? 1 : ((b_ji && !b_ij) ? 2 : 0);
                int nxt  = (c_ij && !c_ji) ? 1 : ((c_ji && !c_ij) ? 2 : 0);
                tok[0] = (float)i; tok[1] = (float)j; tok[2] = (float)prev; tok[3] = (float)nxt;
            } else {
                tok[0] = 0.f; tok[1] = 0.f; tok[2] = 0.f; tok[3] = 0.f;
            }
        }

        // Kahn peeling, double-buffered remW2: ONE barrier per iteration.
        // Hazard audit: iter it reads remW2[it&1] after its sync; the next
        // write to that buffer is at it+2, which is after it+1's sync.
        bool removed = false;
        for (int it = 0; it < KN; ++it) {
            const int bsel = it & 1;
            bool rem = (t < KN) && validT && !removed && (indeg == 0);
            unsigned long long m = __ballot(rem);
            if (wave < 2 && lane == 0) {
                remW2[bsel][wave * 2]     = (uint32_t)m;
                remW2[bsel][wave * 2 + 1] = (uint32_t)(m >> 32);
            }
            __syncthreads();
            uint32_t r0 = remW2[bsel][0], r1 = remW2[bsel][1];
            uint32_t r2 = remW2[bsel][2], r3 = remW2[bsel][3];
            if ((r0 | r1 | r2 | r3) == 0u) break;   // block-uniform
            if (t < 4) removedW[t] |= remW2[bsel][t];
            if (t < KN) {
                indeg -= __popc(r0 & cT0) + __popc(r1 & cT1) +
                         __popc(r2 & cT2) + __popc(r3 & cT3);
                removed = removed || rem;
            }
        }
        __syncthreads();   // removedW final

        if (t == 0) {
            int rc = __popc(removedW[0]) + __popc(removedW[1]) + __popc(removedW[2]) + __popc(removedW[3]);
            int vc = __popc(validW[0]) + __popc(validW[1]) + __popc(validW[2]) + __popc(validW[3]);
            out[ACY_OFF + bc] = ((rc == vc) || (vc <= 1)) ? 1.0f : 0.0f;
        }
    };

    // Stagger keyed on bit 8: alternates across the stride-256 co-resident set.
    if (((bc >> 8) & 1) == 0) {
        rel_expand();
        logic_phase();
    } else {
        logic_phase();
        rel_expand();
    }
}

extern "C" void kernel_launch(void* const* d_in, const int* in_sizes, int n_in,
                              void* d_out, int out_size, void* d_ws, size_t ws_size,
                              hipStream_t stream) {
    const float* A_t  = (const float*)d_in[0];
    const float* cand = (const float*)d_in[1];
    const float* feat = (const float*)d_in[2];
    const float* mask = (const float*)d_in[3];
    float* out = (float*)d_out;
    uint32_t* bits = (uint32_t*)d_ws;   // B*K*4 words = 8 KB

    prep_kernel<<<1024, 256, 0, stream>>>(A_t, feat, bits, out);
    main_kernel<<<BATCH * CAND, 256, 0, stream>>>(cand, mask, bits, out);
}